// Round 2
// baseline (223.528 us; speedup 1.0000x reference)
//
#include <hip/hip_runtime.h>
#include <hip/hip_bf16.h>
#include <stdint.h>

#define NPTS   65536
#define DDIM   128
#define KCODES 1024

typedef __attribute__((ext_vector_type(8))) short     short8;
typedef __attribute__((ext_vector_type(8))) _Float16  half8;
typedef __attribute__((ext_vector_type(4))) float     f32x4;
typedef __attribute__((ext_vector_type(4))) _Float16  half4v;
typedef __attribute__((ext_vector_type(2))) _Float16  half2v;

// ---------------- numeric helpers ----------------
// 2-limb fp16 Dekker split: x ~= (float)hi + (float)lo / 2048.
// hi guarded against fp16-subnormal (tiny x goes entirely to lo, scaled up into
// normal range). lo is fp16-normal except when the residue < 3e-8 (droppable),
// so MFMA fp16 denormal-flush behavior can never matter.
__device__ __forceinline__ void split16(float x, _Float16& hi, _Float16& lo) {
  _Float16 h = (__builtin_fabsf(x) < 6.103515625e-05f) ? (_Float16)0.f : (_Float16)x;
  hi = h;
  lo = (_Float16)(__fmul_rn(__fsub_rn(x, (float)h), 2048.f));  // (x-h) exact; *2^11 exact
}

// numpy pairwise sum of squares for n=128: 8 strided accumulators, 15 sequential
// adds each, then ((r0+r1)+(r2+r3)) + ((r4+r5)+(r6+r7)). Bit-exact np.sum(x*x,-1).
__device__ __forceinline__ float np_sumsq_128(const float* __restrict__ row) {
  float r[8];
#pragma unroll
  for (int k = 0; k < 8; ++k) r[k] = __fmul_rn(row[k], row[k]);
  for (int i = 8; i < 128; i += 8)
#pragma unroll
    for (int k = 0; k < 8; ++k) r[k] = __fadd_rn(r[k], __fmul_rn(row[i + k], row[i + k]));
  float s01 = __fadd_rn(r[0], r[1]), s23 = __fadd_rn(r[2], r[3]);
  float s45 = __fadd_rn(r[4], r[5]), s67 = __fadd_rn(r[6], r[7]);
  return __fadd_rn(__fadd_rn(s01, s23), __fadd_rn(s45, s67));
}

// global->LDS async copy, 16B per lane. LDS dest = wave-uniform base + lane*16.
__device__ __forceinline__ void async_copy16(const void* g, void* l) {
  auto gp = (const __attribute__((address_space(1))) unsigned int*)(uintptr_t)g;
  auto lp = (__attribute__((address_space(3))) unsigned int*)(unsigned)(uintptr_t)l;
  __builtin_amdgcn_global_load_lds(gp, lp, 16, 0, 0);
}

// ---------------- workspace layout ----------------
constexpr size_t SZ_A   = (size_t)NPTS * DDIM * 2;    // 16 MB per A limb
constexpr size_t SZ_B   = (size_t)KCODES * DDIM * 2;  // 256 KB per B limb
constexpr size_t OFF_A1 = 0;
constexpr size_t OFF_A2 = SZ_A;
constexpr size_t OFF_B1 = 2 * SZ_A;
constexpr size_t OFF_B2 = 2 * SZ_A + SZ_B;
constexpr size_t OFF_Z2 = 2 * SZ_A + 2 * SZ_B;
constexpr size_t OFF_C2 = OFF_Z2 + (size_t)NPTS * 4;
constexpr size_t OFF_PK = OFF_C2 + (size_t)KCODES * 4;
constexpr size_t WS_NEED = OFF_PK + (size_t)NPTS * 2 * 8;  // ~35.4 MB

// ---------------- prep: split z into fp16 limbs ----------------
__global__ __launch_bounds__(256) void vq_prep_z(const float4* __restrict__ z4,
                                                 half4v* __restrict__ A1,
                                                 half4v* __restrict__ A2) {
  const int t = blockIdx.x * 256 + threadIdx.x;  // < N*D/4
  float4 v = z4[t];
  _Float16 h0, l0, h1, l1, h2, l2, h3, l3;
  split16(v.x, h0, l0); split16(v.y, h1, l1);
  split16(v.z, h2, l2); split16(v.w, h3, l3);
  A1[t] = (half4v){h0, h1, h2, h3};
  A2[t] = (half4v){l0, l1, l2, l3};
}

// ---------------- prep: z2 per point (numpy pairwise) ----------------
__global__ __launch_bounds__(256) void vq_z2(const float* __restrict__ z,
                                             float* __restrict__ z2) {
  const int p = blockIdx.x * 256 + threadIdx.x;  // < NPTS
  z2[p] = np_sumsq_128(z + (size_t)p * DDIM);
}

// ---------------- prep: codebook limbs + c2 ----------------
__global__ __launch_bounds__(256) void vq_prep_cb(const float* __restrict__ cb,
                                                  _Float16* __restrict__ B1,
                                                  _Float16* __restrict__ B2) {
  const int w = threadIdx.x >> 6, ln = threadIdx.x & 63;
  const int code = blockIdx.x * 4 + w;  // one wave per code row
  const float2 cv = ((const float2*)(cb + (size_t)code * DDIM))[ln];
  _Float16 h0, l0, h1, l1;
  split16(cv.x, h0, l0); split16(cv.y, h1, l1);
  *(half2v*)(B1 + (size_t)code * DDIM + 2 * ln) = (half2v){h0, h1};
  *(half2v*)(B2 + (size_t)code * DDIM + 2 * ln) = (half2v){l0, l1};
}

__global__ __launch_bounds__(256) void vq_c2(const float* __restrict__ cb,
                                             float* __restrict__ c2) {
  const int c = blockIdx.x * 256 + threadIdx.x;  // < KCODES
  c2[c] = np_sumsq_128(cb + (size_t)c * DDIM);
}

// ---------------- main fused GEMM + argmin ----------------
// grid (512, 2): blockIdx.x = 128-point tile, blockIdx.y = 512-code half.
// 4 waves in 2x2, each owns 64x64. Per 128-code block: acc = dot(z,c) via
// 3 exact-product fp16 passes:
//   t 0..3 : a1 * c2s   (scaled 2^11)
//   t 4..7 : a2s * c1   (scaled 2^11)  -> acc *= 2^-11 (exact)
//   t 8..11: a1 * c1
// epilogue replicates np fp32: v = fl(fl(z2 - 2*dot) + c2), argmin first-index.
__global__ __launch_bounds__(256) void vq_gemm(
    const unsigned short* __restrict__ A1, const unsigned short* __restrict__ A2,
    const unsigned short* __restrict__ B1, const unsigned short* __restrict__ B2,
    const float* __restrict__ z2, const float* __restrict__ c2,
    unsigned long long* __restrict__ packed) {
  __shared__ alignas(16) unsigned short As[128 * 32];
  __shared__ alignas(16) unsigned short Bs[128 * 32];
  const int tid = threadIdx.x;
  const int ln = tid & 63, w = tid >> 6;
  const int wr = w >> 1, wc = w & 1;
  const int l15 = ln & 15, q = ln >> 4;
  const size_t row0 = (size_t)blockIdx.x * 128;
  const int half = blockIdx.y;

  const int s0 = tid, s1 = tid + 256;
  const int ar0 = s0 >> 2, ac0 = (s0 & 3) * 8;
  const int ar1 = s1 >> 2, ac1 = (s1 & 3) * 8;

  // z2 for the 16 rows this lane's accumulator slots map to (broadcast loads)
  float z2r[16];
#pragma unroll
  for (int rf = 0; rf < 4; ++rf)
#pragma unroll
    for (int reg = 0; reg < 4; ++reg)
      z2r[rf * 4 + reg] = z2[row0 + wr * 64 + rf * 16 + q * 4 + reg];

  float mv[16];
  int mi[16];
#pragma unroll
  for (int i = 0; i < 16; ++i) { mv[i] = 3.0e38f; mi[i] = 0; }

  for (int cbk = 0; cbk < 4; ++cbk) {
    const int c0 = half * 512 + cbk * 128;
    float c2v[4];
#pragma unroll
    for (int cf = 0; cf < 4; ++cf) c2v[cf] = c2[c0 + wc * 64 + cf * 16 + l15];
    f32x4 acc[4][4];
#pragma unroll
    for (int rf = 0; rf < 4; ++rf)
#pragma unroll
      for (int cf = 0; cf < 4; ++cf) acc[rf][cf] = (f32x4){0.f, 0.f, 0.f, 0.f};

#pragma unroll
    for (int t = 0; t < 12; ++t) {
      const unsigned short* Asrc = (t < 4) ? A1 : ((t < 8) ? A2 : A1);
      const unsigned short* Bsrc = (t < 4) ? B2 : B1;
      const int ko = (t & 3) * 32;
      __syncthreads();
      async_copy16(Asrc + (row0 + ar0) * DDIM + ko + ac0, &As[s0 * 8]);
      async_copy16(Asrc + (row0 + ar1) * DDIM + ko + ac1, &As[s1 * 8]);
      async_copy16(Bsrc + (size_t)(c0 + ar0) * DDIM + ko + ac0, &Bs[s0 * 8]);
      async_copy16(Bsrc + (size_t)(c0 + ar1) * DDIM + ko + ac1, &Bs[s1 * 8]);
      __syncthreads();

      short8 a[4], b[4];
#pragma unroll
      for (int rf = 0; rf < 4; ++rf)
        a[rf] = *(const short8*)&As[(wr * 64 + rf * 16 + l15) * 32 + q * 8];
#pragma unroll
      for (int cf = 0; cf < 4; ++cf)
        b[cf] = *(const short8*)&Bs[(wc * 64 + cf * 16 + l15) * 32 + q * 8];

#pragma unroll
      for (int rf = 0; rf < 4; ++rf)
#pragma unroll
        for (int cf = 0; cf < 4; ++cf)
          acc[rf][cf] = __builtin_amdgcn_mfma_f32_16x16x32_f16(
              __builtin_bit_cast(half8, a[rf]), __builtin_bit_cast(half8, b[cf]),
              acc[rf][cf], 0, 0, 0);

      if (t == 7) {  // exact pow-2 descale of the two lo-limb passes
#pragma unroll
        for (int rf = 0; rf < 4; ++rf)
#pragma unroll
          for (int cf = 0; cf < 4; ++cf)
            acc[rf][cf] = acc[rf][cf] * 4.8828125e-4f;
      }
    }

    // epilogue: np-exact fp32 sequence, fold into running argmin
#pragma unroll
    for (int rf = 0; rf < 4; ++rf)
#pragma unroll
      for (int reg = 0; reg < 4; ++reg) {
        const int slot = rf * 4 + reg;
#pragma unroll
        for (int cf = 0; cf < 4; ++cf) {
          float dot = acc[rf][cf][reg];
          float v = __fadd_rn(__fsub_rn(z2r[slot], __fmul_rn(2.f, dot)), c2v[cf]);
          int idx = c0 + wc * 64 + cf * 16 + l15;
          if (v < mv[slot]) { mv[slot] = v; mi[slot] = idx; }
        }
      }
  }

  // cross-lane argmin over the 16 lanes sharing a row
#pragma unroll
  for (int slot = 0; slot < 16; ++slot) {
    float v = mv[slot];
    int i = mi[slot];
#pragma unroll
    for (int m = 1; m <= 8; m <<= 1) {
      float ov = __shfl_xor(v, m);
      int oi = __shfl_xor(i, m);
      if (ov < v || (ov == v && oi < i)) { v = ov; i = oi; }
    }
    mv[slot] = v; mi[slot] = i;
  }

  __syncthreads();
  float* rv = (float*)As;  // [128][2]
  int* ri = (int*)Bs;
  if (l15 == 0) {
#pragma unroll
    for (int rf = 0; rf < 4; ++rf)
#pragma unroll
      for (int reg = 0; reg < 4; ++reg) {
        const int row = wr * 64 + rf * 16 + q * 4 + reg;
        rv[row * 2 + wc] = mv[rf * 4 + reg];
        ri[row * 2 + wc] = mi[rf * 4 + reg];
      }
  }
  __syncthreads();
  if (tid < 128) {
    float v0 = rv[tid * 2 + 0], v1 = rv[tid * 2 + 1];
    int i0 = ri[tid * 2 + 0], i1 = ri[tid * 2 + 1];
    float v = v0; int i = i0;
    if (v1 < v0 || (v1 == v0 && i1 < i0)) { v = v1; i = i1; }
    unsigned ub = __float_as_uint(v);
    ub = (ub & 0x80000000u) ? ~ub : (ub | 0x80000000u);
    packed[(row0 + tid) * 2 + half] = (((unsigned long long)ub) << 32) | (unsigned)i;
  }
}

// ---------------- merge the two code-halves ----------------
__global__ __launch_bounds__(256) void vq_merge(const unsigned long long* __restrict__ packed,
                                                int* __restrict__ out) {
  const int t = blockIdx.x * 256 + threadIdx.x;
  unsigned long long p0 = packed[2 * t], p1 = packed[2 * t + 1];
  unsigned long long m = p0 < p1 ? p0 : p1;
  out[t] = (int)(unsigned)(m & 0xFFFFFFFFull);
}

// ---------------- fallback (ws too small): fp64 dots + np fp32 formula ----------------
__global__ __launch_bounds__(256) void vq_fallback(const float* __restrict__ z,
                                                   const float* __restrict__ cb,
                                                   int* __restrict__ out) {
  __shared__ float zs[DDIM];
  __shared__ float z2s;
  __shared__ float bv[256];
  __shared__ int bi[256];
  const int p = blockIdx.x, tid = threadIdx.x;
  if (tid < DDIM) zs[tid] = z[(size_t)p * DDIM + tid];
  __syncthreads();
  if (tid == 0) z2s = np_sumsq_128(zs);
  __syncthreads();
  const float z2p = z2s;
  float best = 3.0e38f;
  int bidx = 0;
  for (int c = tid; c < KCODES; c += 256) {
    const float* cr = cb + (size_t)c * DDIM;
    double acc = 0.0;
#pragma unroll 8
    for (int d = 0; d < DDIM; ++d) acc += (double)zs[d] * (double)cr[d];
    float dfl = (float)acc;
    float c2k = np_sumsq_128(cr);
    float v = __fadd_rn(__fsub_rn(z2p, __fmul_rn(2.f, dfl)), c2k);
    if (v < best) { best = v; bidx = c; }
  }
  bv[tid] = best; bi[tid] = bidx;
  __syncthreads();
  for (int off = 128; off > 0; off >>= 1) {
    if (tid < off) {
      if (bv[tid + off] < bv[tid] || (bv[tid + off] == bv[tid] && bi[tid + off] < bi[tid])) {
        bv[tid] = bv[tid + off]; bi[tid] = bi[tid + off];
      }
    }
    __syncthreads();
  }
  if (tid == 0) out[p] = bi[0];
}

// ---------------- launcher ----------------
extern "C" void kernel_launch(void* const* d_in, const int* in_sizes, int n_in,
                              void* d_out, int out_size, void* d_ws, size_t ws_size,
                              hipStream_t stream) {
  (void)in_sizes; (void)n_in; (void)out_size;
  const float* z = (const float*)d_in[0];
  const float* cb = (const float*)d_in[1];
  int* out = (int*)d_out;

  if (d_ws != nullptr && ws_size >= WS_NEED) {
    char* ws = (char*)d_ws;
    half4v* A1 = (half4v*)(ws + OFF_A1);
    half4v* A2 = (half4v*)(ws + OFF_A2);
    _Float16* B1 = (_Float16*)(ws + OFF_B1);
    _Float16* B2 = (_Float16*)(ws + OFF_B2);
    float* z2 = (float*)(ws + OFF_Z2);
    float* c2 = (float*)(ws + OFF_C2);
    unsigned long long* pk = (unsigned long long*)(ws + OFF_PK);

    vq_prep_z<<<(NPTS * DDIM / 4) / 256, 256, 0, stream>>>((const float4*)z, A1, A2);
    vq_z2<<<NPTS / 256, 256, 0, stream>>>(z, z2);
    vq_prep_cb<<<KCODES / 4, 256, 0, stream>>>(cb, B1, B2);
    vq_c2<<<KCODES / 256, 256, 0, stream>>>(cb, c2);
    vq_gemm<<<dim3(NPTS / 128, 2), 256, 0, stream>>>(
        (const unsigned short*)(ws + OFF_A1), (const unsigned short*)(ws + OFF_A2),
        (const unsigned short*)(ws + OFF_B1), (const unsigned short*)(ws + OFF_B2),
        z2, c2, pk);
    vq_merge<<<NPTS / 256, 256, 0, stream>>>(pk, out);
  } else {
    vq_fallback<<<NPTS, 256, 0, stream>>>(z, cb, out);
  }
}